// Round 1
// baseline (4807.830 us; speedup 1.0000x reference)
//
#include <hip/hip_runtime.h>
#include <hip/hip_bf16.h>

#define DD 300
#define TS 64
#define TK 16

// ---------- order-preserving float<->uint map (for exact atomic max) ----------
__device__ __forceinline__ unsigned fmap(float x) {
    unsigned b = __float_as_uint(x);
    return (b & 0x80000000u) ? ~b : (b | 0x80000000u);
}
__device__ __forceinline__ float funmap(unsigned u) {
    unsigned b = (u & 0x80000000u) ? (u ^ 0x80000000u) : ~u;
    return __uint_as_float(b);
}

// ---------- generic tiled fp32 GEMM: C = A[M,K] @ B[K,N] (+bias)(+rank3)(+resid)(relu) ----------
template<int RELU, int RESID, int RANK3>
__launch_bounds__(256)
__global__ void gemm_f32(const float* __restrict__ A, const float* __restrict__ B,
                         const float* __restrict__ bias, const float* __restrict__ resid,
                         const float* __restrict__ P3, const float* __restrict__ W3,
                         float* __restrict__ C, int M, int N, int K)
{
    __shared__ float As[TS][TK + 1];
    __shared__ float Bs[TK][TS];
    const int tid = threadIdx.x;
    const int tx = tid & 15, ty = tid >> 4;
    const int rowBase = blockIdx.y * TS;
    const int colBase = blockIdx.x * TS;
    float acc[4][4] = {};

    for (int k0 = 0; k0 < K; k0 += TK) {
        #pragma unroll
        for (int i = 0; i < 4; ++i) {
            int e = tid * 4 + i;
            int r = e >> 4, c = e & 15;
            int gr = rowBase + r, gc = k0 + c;
            As[r][c] = (gr < M && gc < K) ? A[(long)gr * K + gc] : 0.f;
        }
        #pragma unroll
        for (int i = 0; i < 4; ++i) {
            int e = tid * 4 + i;
            int r = e >> 6, c = e & 63;
            int gr = k0 + r, gc = colBase + c;
            Bs[r][c] = (gr < K && gc < N) ? B[(long)gr * N + gc] : 0.f;
        }
        __syncthreads();
        #pragma unroll
        for (int kk = 0; kk < TK; ++kk) {
            float a[4], b[4];
            #pragma unroll
            for (int i = 0; i < 4; ++i) a[i] = As[ty * 4 + i][kk];
            #pragma unroll
            for (int j = 0; j < 4; ++j) b[j] = Bs[kk][tx * 4 + j];
            #pragma unroll
            for (int i = 0; i < 4; ++i)
                #pragma unroll
                for (int j = 0; j < 4; ++j)
                    acc[i][j] += a[i] * b[j];
        }
        __syncthreads();
    }

    #pragma unroll
    for (int i = 0; i < 4; ++i) {
        int gr = rowBase + ty * 4 + i;
        if (gr >= M) continue;
        #pragma unroll
        for (int j = 0; j < 4; ++j) {
            int gc = colBase + tx * 4 + j;
            if (gc >= N) continue;
            float v = acc[i][j];
            if (bias) v += bias[gc];
            if (RANK3) {
                #pragma unroll
                for (int r = 0; r < 3; ++r)
                    v += P3[(long)gr * 3 + r] * W3[r * N + gc];
            }
            if (RESID) v += resid[(long)gr * N + gc];
            if (RELU) v = fmaxf(v, 0.f);
            C[(long)gr * N + gc] = v;
        }
    }
}

// ---------- delta = h @ hW[300,3] + hb : one wave per node ----------
__global__ void delta_kernel(const float* __restrict__ h, const float* __restrict__ hW,
                             const float* __restrict__ hb, float* __restrict__ dlt, int Nn)
{
    int gw = (blockIdx.x * blockDim.x + threadIdx.x) >> 6;
    int lane = threadIdx.x & 63;
    if (gw >= Nn) return;
    const float* hr = h + (long)gw * DD;
    float a0 = 0.f, a1 = 0.f, a2 = 0.f;
    for (int c = lane; c < DD; c += 64) {
        float hv = hr[c];
        a0 += hv * hW[c * 3 + 0];
        a1 += hv * hW[c * 3 + 1];
        a2 += hv * hW[c * 3 + 2];
    }
    #pragma unroll
    for (int o = 32; o; o >>= 1) {
        a0 += __shfl_down(a0, o);
        a1 += __shfl_down(a1, o);
        a2 += __shfl_down(a2, o);
    }
    if (lane == 0) {
        dlt[gw * 3 + 0] = a0 + hb[0];
        dlt[gw * 3 + 1] = a1 + hb[1];
        dlt[gw * 3 + 2] = a2 + hb[2];
    }
}

// ---------- fill uint buffer with a constant ----------
__global__ void fill_kernel(unsigned* __restrict__ p, unsigned val, int n)
{
    int i = blockIdx.x * blockDim.x + threadIdx.x;
    if (i < n) p[i] = val;
}

__global__ void zero_kernel(float* __restrict__ p, int n)
{
    int i = blockIdx.x * blockDim.x + threadIdx.x;
    if (i < n) p[i] = 0.f;
}

// ---------- segment max of u[src] into M[dst] : one wave per edge ----------
__global__ void edge_max_kernel(const float* __restrict__ u, const int* __restrict__ src,
                                const int* __restrict__ dst, unsigned* __restrict__ Mb, int E)
{
    int gw = (blockIdx.x * blockDim.x + threadIdx.x) >> 6;
    int lane = threadIdx.x & 63;
    if (gw >= E) return;
    int s = src[gw], d = dst[gw];
    const float* ur = u + (long)s * DD;
    unsigned* mr = Mb + (long)d * DD;
    for (int c = lane; c < DD; c += 64)
        atomicMax(mr + c, fmap(ur[c]));
}

// ---------- agg = isfinite(M) ? M + (delta-pos)@fWp + fb : 0   (in place ok) ----------
__global__ void agg_kernel(const unsigned* Mb, const float* __restrict__ dlt,
                           const float* __restrict__ pos, const float* __restrict__ fWp,
                           const float* __restrict__ fb, float* aggOut, int total)
{
    int idx = blockIdx.x * blockDim.x + threadIdx.x;
    if (idx >= total) return;
    int n = idx / DD, c = idx - n * DD;
    float m = funmap(Mb[idx]);
    float out = 0.f;
    if (m != -INFINITY) {
        float v = 0.f;
        #pragma unroll
        for (int r = 0; r < 3; ++r)
            v += (dlt[n * 3 + r] - pos[n * 3 + r]) * fWp[r * DD + c];
        out = m + v + fb[c];
    }
    aggOut[idx] = out;
}

// ---------- global mean pool partials: sorted-batch run-length + atomics ----------
__global__ void pool_kernel(const float* __restrict__ h, const int* __restrict__ batch,
                            float* __restrict__ sums, float* __restrict__ cnts,
                            int Nn, int npb)
{
    int c = threadIdx.x;
    int n0 = blockIdx.x * npb;
    int n1 = min(n0 + npb, Nn);
    if (n0 >= n1) return;
    if (c < DD) {
        float run = 0.f;
        int g = batch[n0];
        for (int n = n0; n < n1; ++n) {
            int gn = batch[n];
            if (gn != g) { atomicAdd(&sums[g * DD + c], run); run = 0.f; g = gn; }
            run += h[(long)n * DD + c];
        }
        atomicAdd(&sums[g * DD + c], run);
    } else if (c == DD) {
        float run = 0.f;
        int g = batch[n0];
        for (int n = n0; n < n1; ++n) {
            int gn = batch[n];
            if (gn != g) { atomicAdd(&cnts[g], run); run = 0.f; g = gn; }
            run += 1.f;
        }
        atomicAdd(&cnts[g], run);
    }
}

// ---------- head: mean -> logits -> log_softmax ----------
__global__ void head_kernel(const float* __restrict__ sums, const float* __restrict__ cnts,
                            const float* __restrict__ dW, const float* __restrict__ db,
                            float* __restrict__ out)
{
    __shared__ float mean[32][DD];
    __shared__ float logits[32][40];
    int tid = threadIdx.x;
    for (int i = tid; i < 32 * DD; i += 256) {
        int g = i / DD;
        mean[g][i - g * DD] = sums[i] / fmaxf(cnts[g], 1.f);
    }
    __syncthreads();
    for (int o = tid; o < 32 * 40; o += 256) {
        int g = o / 40, cls = o - g * 40;
        float acc = db[cls];
        for (int k = 0; k < DD; ++k) acc += mean[g][k] * dW[k * 40 + cls];
        logits[g][cls] = acc;
    }
    __syncthreads();
    if (tid < 32) {
        float mx = -INFINITY;
        #pragma unroll
        for (int j = 0; j < 40; ++j) mx = fmaxf(mx, logits[tid][j]);
        float se = 0.f;
        for (int j = 0; j < 40; ++j) se += expf(logits[tid][j] - mx);
        float lse = mx + logf(se);
        for (int j = 0; j < 40; ++j) out[tid * 40 + j] = logits[tid][j] - lse;
    }
}

extern "C" void kernel_launch(void* const* d_in, const int* in_sizes, int n_in,
                              void* d_out, int out_size, void* d_ws, size_t ws_size,
                              hipStream_t stream)
{
    const float* x     = (const float*)d_in[0];
    const int*   ei    = (const int*)d_in[1];
    const int*   batch = (const int*)d_in[2];
    const float* pW1   = (const float*)d_in[3];
    const float* pb1   = (const float*)d_in[4];
    const float* pW2   = (const float*)d_in[5];
    const float* pb2   = (const float*)d_in[6];
    const float* pW3   = (const float*)d_in[7];
    const float* pb3   = (const float*)d_in[8];
    const float* hW    = (const float*)d_in[9];
    const float* hb    = (const float*)d_in[10];
    const float* fW    = (const float*)d_in[11];
    const float* fb    = (const float*)d_in[12];
    const float* gW    = (const float*)d_in[13];
    const float* gb    = (const float*)d_in[14];
    const float* lW    = (const float*)d_in[15];
    const float* lb    = (const float*)d_in[16];
    const float* dW    = (const float*)d_in[17];
    const float* db    = (const float*)d_in[18];

    const int N = in_sizes[0] / 3;
    const int E = in_sizes[1] / 2;
    const int G = 32;

    char* wsb = (char*)d_ws;
    size_t off = 0;
    auto alloc = [&](size_t bytes) {
        void* p = wsb + off;
        off += (bytes + 255) & ~(size_t)255;
        return p;
    };
    float* buf0 = (float*)alloc((size_t)N * DD * 4);
    float* buf1 = (float*)alloc((size_t)N * DD * 4);
    float* buf2 = (float*)alloc((size_t)N * DD * 4);
    float* dlt  = (float*)alloc((size_t)N * 3 * 4);
    float* sums = (float*)alloc((size_t)G * DD * 4);
    float* cnts = (float*)alloc((size_t)G * 4);
    (void)ws_size; (void)n_in; (void)out_size;

    const dim3 blk(256);
    auto gemmGrid = [&](int M_, int N_) { return dim3((N_ + TS - 1) / TS, (M_ + TS - 1) / TS); };

    // ---- embed MLP: 3 -> 64 -> 128 -> 300 ----
    gemm_f32<1,0,0><<<gemmGrid(N, 64),  blk, 0, stream>>>(x,    pW1, pb1, nullptr, nullptr, nullptr, buf1, N, 64,  3);
    gemm_f32<1,0,0><<<gemmGrid(N, 128), blk, 0, stream>>>(buf1, pW2, pb2, nullptr, nullptr, nullptr, buf2, N, 128, 64);
    gemm_f32<0,0,0><<<gemmGrid(N, DD),  blk, 0, stream>>>(buf2, pW3, pb3, nullptr, nullptr, nullptr, buf0, N, DD,  128);

    const int* srcp = ei;
    const int* dstp = ei + E;

    for (int i = 0; i < 3; ++i) {
        const float* hWi = hW + (size_t)i * DD * 3;
        const float* hbi = hb + (size_t)i * 3;
        const float* fWi = fW + (size_t)i * (DD + 3) * DD;
        const float* fbi = fb + (size_t)i * DD;
        const float* gWi = gW + (size_t)i * DD * DD;
        const float* gbi = gb + (size_t)i * DD;
        const float* lWi = lW + (size_t)i * DD * DD;
        const float* lbi = lb + (size_t)i * DD;
        const float* fWp = fWi;          // rows 0..2 (pos part of concat)
        const float* fWh = fWi + 3 * DD; // rows 3..302 (h part)

        // delta = h @ hW + hb
        delta_kernel<<<dim3((N + 3) / 4), blk, 0, stream>>>(buf0, hWi, hbi, dlt, N);
        // u = h @ fWh + pos @ fWp   (src-side node projection)
        gemm_f32<0,0,1><<<gemmGrid(N, DD), blk, 0, stream>>>(buf0, fWh, nullptr, nullptr, x, fWp, buf1, N, DD, DD);
        // M = segment_max(u[src], dst)
        fill_kernel<<<dim3((N * DD + 255) / 256), blk, 0, stream>>>((unsigned*)buf2, 0x007FFFFFu, N * DD);
        edge_max_kernel<<<dim3((E + 3) / 4), blk, 0, stream>>>(buf1, srcp, dstp, (unsigned*)buf2, E);
        // agg = isfinite ? M + (delta-pos)@fWp + fb : 0
        agg_kernel<<<dim3((N * DD + 255) / 256), blk, 0, stream>>>((unsigned*)buf2, dlt, x, fWp, fbi, buf2, N * DD);
        // h = relu(agg @ gW + gb + h)
        gemm_f32<1,1,0><<<gemmGrid(N, DD), blk, 0, stream>>>(buf2, gWi, gbi, buf0, nullptr, nullptr, buf1, N, DD, DD);
        // h = h @ lW + lb
        gemm_f32<0,0,0><<<gemmGrid(N, DD), blk, 0, stream>>>(buf1, lWi, lbi, nullptr, nullptr, nullptr, buf0, N, DD, DD);
    }

    // ---- global mean pool + head ----
    zero_kernel<<<dim3((G * DD + 255) / 256), blk, 0, stream>>>(sums, G * DD);
    zero_kernel<<<dim3(1), blk, 0, stream>>>(cnts, G);
    pool_kernel<<<dim3((N + 127) / 128), dim3(320), 0, stream>>>(buf0, batch, sums, cnts, N, 128);
    head_kernel<<<dim3(1), dim3(256), 0, stream>>>(sums, cnts, dW, db, (float*)d_out);
}

// Round 2
// 966.424 us; speedup vs baseline: 4.9749x; 4.9749x over previous
//
#include <hip/hip_runtime.h>
#include <hip/hip_bf16.h>

#define DD 300
#define DP 320   // padded feature width

typedef unsigned short ushort_t;
typedef __attribute__((ext_vector_type(8))) short short8;
typedef __attribute__((ext_vector_type(4))) float f32x4;

__device__ __forceinline__ float b2f(ushort_t u) {
    unsigned x = ((unsigned)u) << 16;
    return __uint_as_float(x);
}
__device__ __forceinline__ ushort_t f2b(float f) {
    unsigned u = __float_as_uint(f);
    unsigned r = (u + 0x7FFFu + ((u >> 16) & 1u)) >> 16;
    return (ushort_t)r;
}

__device__ __forceinline__ void gload16(const void* g, void* l) {
    __builtin_amdgcn_global_load_lds((const __attribute__((address_space(1))) void*)g,
                                     (__attribute__((address_space(3))) void*)l, 16, 0, 0);
}

// ================= MFMA bf16 GEMM =================
// C[M][NCtot] = A[M][K](bf16, stride=K) @ Bt^T  where Bt is [NCtot][K] bf16 (pre-transposed, padded)
// BM=128, BK=64, BN=32*BNT, 512 threads = 8 waves (4 row-waves x 2 col-waves)
template<int BNT, int BIAS, int RELU, int RESID, int RANK3>
__launch_bounds__(512)
__global__ void gemm_mfma(const ushort_t* __restrict__ A, int strideA, int M, int K,
                          const ushort_t* __restrict__ Bt,
                          const float* __restrict__ bias,
                          const ushort_t* __restrict__ resid,
                          const float* __restrict__ X3,
                          const float* __restrict__ W3,
                          int NCOL,
                          ushort_t* __restrict__ C, int strideC)
{
    constexpr int BM = 128, BK = 64, BN = 32 * BNT;
    constexpr int CA = BM * BK * 2 / 1024;  // A chunks (1KB each)
    constexpr int CB = BN * BK * 2 / 1024;  // B chunks
    __shared__ ushort_t As[BM * BK];
    __shared__ ushort_t Bs[BN * BK];

    const int tid = threadIdx.x;
    const int lane = tid & 63, wid = tid >> 6;
    const int rowTile = blockIdx.y * BM;
    const int colTile = blockIdx.x * BN;
    const int wm = wid >> 1, wn = wid & 1;

    const int lrow = lane >> 3;          // row within 8-row chunk
    const int l8b = (lane & 7) * 16;     // physical 16B slot within 128B row

    f32x4 acc[2][BNT];
    #pragma unroll
    for (int f = 0; f < 2; ++f)
        #pragma unroll
        for (int q = 0; q < BNT; ++q) {
            f32x4 z = {0.f, 0.f, 0.f, 0.f};
            acc[f][q] = z;
        }

    for (int k0 = 0; k0 < K; k0 += BK) {
        // stage A (pre-swizzled global source -> linear LDS dest)
        for (int c = wid; c < CA; c += 8) {
            int row = c * 8 + lrow;
            int colb = l8b ^ ((row & 7) << 4);
            int gr = rowTile + row; if (gr > M - 1) gr = M - 1;
            gload16(A + (size_t)gr * strideA + k0 + (colb >> 1), As + c * 512);
        }
        // stage Bt
        for (int c = wid; c < CB; c += 8) {
            int row = c * 8 + lrow;
            int colb = l8b ^ ((row & 7) << 4);
            gload16(Bt + (size_t)(colTile + row) * K + k0 + (colb >> 1), Bs + c * 512);
        }
        __syncthreads();

        #pragma unroll
        for (int ks = 0; ks < 2; ++ks) {
            const int kidx = ks * 32 + (lane >> 4) * 8;
            short8 af[2], bf[BNT];
            #pragma unroll
            for (int f = 0; f < 2; ++f) {
                int row = wm * 32 + f * 16 + (lane & 15);
                int phys = (row * 128 + kidx * 2) ^ ((row & 7) << 4);
                af[f] = *(const short8*)((const char*)As + phys);
            }
            #pragma unroll
            for (int q = 0; q < BNT; ++q) {
                int row = wn * 16 * BNT + q * 16 + (lane & 15);
                int phys = (row * 128 + kidx * 2) ^ ((row & 7) << 4);
                bf[q] = *(const short8*)((const char*)Bs + phys);
            }
            #pragma unroll
            for (int f = 0; f < 2; ++f)
                #pragma unroll
                for (int q = 0; q < BNT; ++q)
                    acc[f][q] = __builtin_amdgcn_mfma_f32_16x16x32_bf16(af[f], bf[q], acc[f][q], 0, 0, 0);
        }
        __syncthreads();
    }

    // epilogue
    #pragma unroll
    for (int f = 0; f < 2; ++f) {
        #pragma unroll
        for (int r = 0; r < 4; ++r) {
            int row = rowTile + wm * 32 + f * 16 + (lane >> 4) * 4 + r;
            if (row >= M) continue;
            #pragma unroll
            for (int q = 0; q < BNT; ++q) {
                int col = colTile + wn * 16 * BNT + q * 16 + (lane & 15);
                float v = acc[f][q][r];
                if (BIAS) v += (col < NCOL) ? bias[col] : 0.f;
                if (RANK3) {
                    if (col < NCOL) {
                        v += X3[row * 3 + 0] * W3[col]
                           + X3[row * 3 + 1] * W3[NCOL + col]
                           + X3[row * 3 + 2] * W3[2 * NCOL + col];
                    }
                }
                if (RESID) v += b2f(resid[(size_t)row * strideC + col]);
                if (RELU) v = fmaxf(v, 0.f);
                C[(size_t)row * strideC + col] = f2b(v);
            }
        }
    }
}

// ============ weight transpose/pad/bf16: W[K][N] (+rowoff) -> Bt[Np][Kp] ============
__global__ void wconv(const float* __restrict__ W, int K, int N, int rowoff,
                      ushort_t* __restrict__ Bt, int Kp, int Np)
{
    int idx = blockIdx.x * 256 + threadIdx.x;
    if (idx >= Kp * Np) return;
    int n = idx / Kp, k = idx - n * Kp;
    float v = (k < K && n < N) ? W[(size_t)(k + rowoff) * N + n] : 0.f;
    Bt[idx] = f2b(v);
}

// ============ embed layer 1: h1 = relu(x @ pW1 + pb1), K=3 ============
__global__ void embed1(const float* __restrict__ x, const float* __restrict__ W,
                       const float* __restrict__ b, ushort_t* __restrict__ h1, int M)
{
    int idx = blockIdx.x * 256 + threadIdx.x;
    if (idx >= M * 64) return;
    int n = idx >> 6, c = idx & 63;
    const float* xr = x + n * 3;
    float v = xr[0] * W[c] + xr[1] * W[64 + c] + xr[2] * W[128 + c] + b[c];
    h1[idx] = f2b(fmaxf(v, 0.f));
}

// ============ delta = h @ hW[300,3] + hb : one wave per node (bf16 h) ============
__global__ void delta_kernel(const ushort_t* __restrict__ h, const float* __restrict__ hW,
                             const float* __restrict__ hb, float* __restrict__ dlt, int Nn)
{
    int gw = (blockIdx.x * blockDim.x + threadIdx.x) >> 6;
    int lane = threadIdx.x & 63;
    if (gw >= Nn) return;
    const ushort_t* hr = h + (size_t)gw * DP;
    float a0 = 0.f, a1 = 0.f, a2 = 0.f;
    for (int c = lane; c < DD; c += 64) {
        float hv = b2f(hr[c]);
        a0 += hv * hW[c * 3 + 0];
        a1 += hv * hW[c * 3 + 1];
        a2 += hv * hW[c * 3 + 2];
    }
    #pragma unroll
    for (int o = 32; o; o >>= 1) {
        a0 += __shfl_down(a0, o);
        a1 += __shfl_down(a1, o);
        a2 += __shfl_down(a2, o);
    }
    if (lane == 0) {
        dlt[gw * 3 + 0] = a0 + hb[0];
        dlt[gw * 3 + 1] = a1 + hb[1];
        dlt[gw * 3 + 2] = a2 + hb[2];
    }
}

// ============ CSR build ============
__global__ void zero_i(int* __restrict__ p, int n)
{
    int i = blockIdx.x * 256 + threadIdx.x;
    if (i < n) p[i] = 0;
}
__global__ void zero_f(float* __restrict__ p, int n)
{
    int i = blockIdx.x * 256 + threadIdx.x;
    if (i < n) p[i] = 0.f;
}
__global__ void hist_kernel(const int* __restrict__ dst, int* __restrict__ cnt, int E)
{
    int e = blockIdx.x * 256 + threadIdx.x;
    if (e < E) atomicAdd(&cnt[dst[e]], 1);
}
__global__ void scan1(const int* __restrict__ cnt, int* __restrict__ bsum, int N)
{
    __shared__ int s[256];
    int t = threadIdx.x;
    int i = blockIdx.x * 256 + t;
    s[t] = (i < N) ? cnt[i] : 0;
    __syncthreads();
    for (int o = 128; o > 0; o >>= 1) { if (t < o) s[t] += s[t + o]; __syncthreads(); }
    if (t == 0) bsum[blockIdx.x] = s[0];
}
__global__ void scan2(int* __restrict__ bsum, int nb)
{
    __shared__ int s[256];
    int t = threadIdx.x;
    int v = (t < nb) ? bsum[t] : 0;
    s[t] = v; __syncthreads();
    for (int o = 1; o < 256; o <<= 1) {
        int x = (t >= o) ? s[t - o] : 0;
        __syncthreads();
        s[t] += x;
        __syncthreads();
    }
    if (t < nb) bsum[t] = s[t] - v;
}
__global__ void scan3(const int* __restrict__ cnt, const int* __restrict__ bsumx,
                      int* __restrict__ off, int* __restrict__ cursor, int N)
{
    __shared__ int s[256];
    int t = threadIdx.x;
    int i = blockIdx.x * 256 + t;
    int v = (i < N) ? cnt[i] : 0;
    s[t] = v; __syncthreads();
    for (int o = 1; o < 256; o <<= 1) {
        int x = (t >= o) ? s[t - o] : 0;
        __syncthreads();
        s[t] += x;
        __syncthreads();
    }
    int excl = s[t] - v + bsumx[blockIdx.x];
    if (i <= N) {
        off[i] = excl;
        if (i < N) cursor[i] = excl;
    }
}
__global__ void scatter_kernel(const int* __restrict__ src, const int* __restrict__ dst,
                               int* __restrict__ cursor, int* __restrict__ csr, int E)
{
    int e = blockIdx.x * 256 + threadIdx.x;
    if (e < E) {
        int p = atomicAdd(&cursor[dst[e]], 1);
        csr[p] = src[e];
    }
}

// ============ segment max over CSR, fused dst-side epilogue ============
// agg[n][c] = deg>0 && c<300 ? max_e u[csr[e]][c] + fb[c] + (delta[n]-pos[n]).fWp[:,c] : 0
__global__ void segmax(const ushort_t* __restrict__ u, const int* __restrict__ off,
                       const int* __restrict__ csr, const float* __restrict__ dlt,
                       const float* __restrict__ x, const float* __restrict__ fWp,
                       const float* __restrict__ fb, ushort_t* __restrict__ agg, int Nn)
{
    int n = blockIdx.x * 4 + (threadIdx.x >> 6);
    int lane = threadIdx.x & 63;
    if (n >= Nn) return;
    int e0 = off[n], e1 = off[n + 1];
    float m[5];
    #pragma unroll
    for (int j = 0; j < 5; ++j) m[j] = -INFINITY;
    for (int e = e0; e < e1; ++e) {
        const ushort_t* ur = u + (size_t)csr[e] * DP;
        #pragma unroll
        for (int j = 0; j < 5; ++j)
            m[j] = fmaxf(m[j], b2f(ur[lane + 64 * j]));
    }
    float d0 = dlt[n * 3 + 0] - x[n * 3 + 0];
    float d1 = dlt[n * 3 + 1] - x[n * 3 + 1];
    float d2 = dlt[n * 3 + 2] - x[n * 3 + 2];
    #pragma unroll
    for (int j = 0; j < 5; ++j) {
        int col = lane + 64 * j;
        float o = 0.f;
        if (e1 > e0 && col < DD)
            o = m[j] + fb[col] + d0 * fWp[col] + d1 * fWp[DD + col] + d2 * fWp[2 * DD + col];
        agg[(size_t)n * DP + col] = f2b(o);
    }
}

// ============ global mean pool (bf16 h) ============
__global__ void pool_kernel(const ushort_t* __restrict__ h, const int* __restrict__ batch,
                            float* __restrict__ sums, float* __restrict__ cnts,
                            int Nn, int npb)
{
    int c = threadIdx.x;
    int n0 = blockIdx.x * npb;
    int n1 = min(n0 + npb, Nn);
    if (n0 >= n1) return;
    if (c < DD) {
        float run = 0.f;
        int g = batch[n0];
        for (int n = n0; n < n1; ++n) {
            int gn = batch[n];
            if (gn != g) { atomicAdd(&sums[g * DD + c], run); run = 0.f; g = gn; }
            run += b2f(h[(size_t)n * DP + c]);
        }
        atomicAdd(&sums[g * DD + c], run);
    } else if (c == DD) {
        float run = 0.f;
        int g = batch[n0];
        for (int n = n0; n < n1; ++n) {
            int gn = batch[n];
            if (gn != g) { atomicAdd(&cnts[g], run); run = 0.f; g = gn; }
            run += 1.f;
        }
        atomicAdd(&cnts[g], run);
    }
}

// ============ head: mean -> logits -> log_softmax ============
__global__ void head_kernel(const float* __restrict__ sums, const float* __restrict__ cnts,
                            const float* __restrict__ dW, const float* __restrict__ db,
                            float* __restrict__ out)
{
    __shared__ float mean[32][DD];
    __shared__ float logits[32][40];
    int tid = threadIdx.x;
    for (int i = tid; i < 32 * DD; i += 256) {
        int g = i / DD;
        mean[g][i - g * DD] = sums[i] / fmaxf(cnts[g], 1.f);
    }
    __syncthreads();
    for (int o = tid; o < 32 * 40; o += 256) {
        int g = o / 40, cls = o - g * 40;
        float acc = db[cls];
        for (int k = 0; k < DD; ++k) acc += mean[g][k] * dW[k * 40 + cls];
        logits[g][cls] = acc;
    }
    __syncthreads();
    if (tid < 32) {
        float mx = -INFINITY;
        #pragma unroll
        for (int j = 0; j < 40; ++j) mx = fmaxf(mx, logits[tid][j]);
        float se = 0.f;
        for (int j = 0; j < 40; ++j) se += expf(logits[tid][j] - mx);
        float lse = mx + logf(se);
        for (int j = 0; j < 40; ++j) out[tid * 40 + j] = logits[tid][j] - lse;
    }
}

extern "C" void kernel_launch(void* const* d_in, const int* in_sizes, int n_in,
                              void* d_out, int out_size, void* d_ws, size_t ws_size,
                              hipStream_t stream)
{
    const float* x     = (const float*)d_in[0];
    const int*   ei    = (const int*)d_in[1];
    const int*   batch = (const int*)d_in[2];
    const float* pW1   = (const float*)d_in[3];
    const float* pb1   = (const float*)d_in[4];
    const float* pW2   = (const float*)d_in[5];
    const float* pb2   = (const float*)d_in[6];
    const float* pW3   = (const float*)d_in[7];
    const float* pb3   = (const float*)d_in[8];
    const float* hW    = (const float*)d_in[9];
    const float* hb    = (const float*)d_in[10];
    const float* fW    = (const float*)d_in[11];
    const float* fb    = (const float*)d_in[12];
    const float* gW    = (const float*)d_in[13];
    const float* gb    = (const float*)d_in[14];
    const float* lW    = (const float*)d_in[15];
    const float* lb    = (const float*)d_in[16];
    const float* dW    = (const float*)d_in[17];
    const float* db    = (const float*)d_in[18];

    const int N = in_sizes[0] / 3;
    const int E = in_sizes[1] / 2;
    const int G = 32;
    (void)ws_size; (void)n_in; (void)out_size;

    char* wsb = (char*)d_ws;
    size_t offb = 0;
    auto alloc = [&](size_t bytes) {
        void* p = wsb + offb;
        offb += (bytes + 255) & ~(size_t)255;
        return p;
    };
    ushort_t* h    = (ushort_t*)alloc((size_t)N * DP * 2);
    ushort_t* u    = (ushort_t*)alloc((size_t)N * DP * 2);
    ushort_t* agg  = (ushort_t*)alloc((size_t)N * DP * 2);
    ushort_t* h1   = (ushort_t*)alloc((size_t)N * 64 * 2);
    ushort_t* h2   = (ushort_t*)alloc((size_t)N * 128 * 2);
    float*    dlt  = (float*)alloc((size_t)N * 3 * 4);
    ushort_t* wbuf = (ushort_t*)alloc((size_t)DP * DP * 2);
    int*      cnt    = (int*)alloc((size_t)(N + 1) * 4);
    int*      offp   = (int*)alloc((size_t)(N + 1) * 4);
    int*      cursor = (int*)alloc((size_t)N * 4);
    int*      bsum   = (int*)alloc((size_t)256 * 4);
    int*      csr    = (int*)alloc((size_t)E * 4);
    float*    sums   = (float*)alloc((size_t)G * DD * 4);
    float*    cnts   = (float*)alloc((size_t)G * 4);

    const int* srcp = ei;
    const int* dstp = ei + E;
    const int nb = (N + 255) / 256;
    const dim3 blk(256);

    // ---- CSR build (once; reused by all 3 layers) ----
    zero_i<<<dim3((N + 1 + 255) / 256), blk, 0, stream>>>(cnt, N + 1);
    hist_kernel<<<dim3((E + 255) / 256), blk, 0, stream>>>(dstp, cnt, E);
    scan1<<<dim3(nb), blk, 0, stream>>>(cnt, bsum, N);
    scan2<<<dim3(1), blk, 0, stream>>>(bsum, nb);
    scan3<<<dim3(nb), blk, 0, stream>>>(cnt, bsum, offp, cursor, N);
    scatter_kernel<<<dim3((E + 255) / 256), blk, 0, stream>>>(srcp, dstp, cursor, csr, E);

    // ---- embed MLP ----
    embed1<<<dim3((N * 64 + 255) / 256), blk, 0, stream>>>(x, pW1, pb1, h1, N);

    const int rowBlocks = (N + 127) / 128;
    wconv<<<dim3((64 * 128 + 255) / 256), blk, 0, stream>>>(pW2, 64, 128, 0, wbuf, 64, 128);
    gemm_mfma<4, 1, 1, 0, 0><<<dim3(1, rowBlocks), dim3(512), 0, stream>>>(
        h1, 64, N, 64, wbuf, pb2, nullptr, nullptr, nullptr, 128, h2, 128);
    wconv<<<dim3((128 * DP + 255) / 256), blk, 0, stream>>>(pW3, 128, DD, 0, wbuf, 128, DP);
    gemm_mfma<5, 1, 0, 0, 0><<<dim3(2, rowBlocks), dim3(512), 0, stream>>>(
        h2, 128, N, 128, wbuf, pb3, nullptr, nullptr, nullptr, DD, h, DP);

    // ---- 3 PointGNNConv layers ----
    for (int i = 0; i < 3; ++i) {
        const float* hWi = hW + (size_t)i * DD * 3;
        const float* hbi = hb + (size_t)i * 3;
        const float* fWi = fW + (size_t)i * (DD + 3) * DD;
        const float* fbi = fb + (size_t)i * DD;
        const float* gWi = gW + (size_t)i * DD * DD;
        const float* gbi = gb + (size_t)i * DD;
        const float* lWi = lW + (size_t)i * DD * DD;
        const float* lbi = lb + (size_t)i * DD;

        // delta = h @ hW + hb
        delta_kernel<<<dim3((N + 3) / 4), blk, 0, stream>>>(h, hWi, hbi, dlt, N);

        // u = h @ fWh + x @ fWp  (src-side projection), bf16 out
        wconv<<<dim3((DP * DP + 255) / 256), blk, 0, stream>>>(fWi, DD, DD, 3, wbuf, DP, DP);
        gemm_mfma<5, 0, 0, 0, 1><<<dim3(2, rowBlocks), dim3(512), 0, stream>>>(
            h, DP, N, DP, wbuf, nullptr, nullptr, x, fWi, DD, u, DP);

        // agg = segment_max(u[src], dst) + dst-side terms
        segmax<<<dim3((N + 3) / 4), blk, 0, stream>>>(u, offp, csr, dlt, x, fWi, fbi, agg, N);

        // t = relu(agg @ gW + gb + h)  -> write into u buffer
        wconv<<<dim3((DP * DP + 255) / 256), blk, 0, stream>>>(gWi, DD, DD, 0, wbuf, DP, DP);
        gemm_mfma<5, 1, 1, 1, 0><<<dim3(2, rowBlocks), dim3(512), 0, stream>>>(
            agg, DP, N, DP, wbuf, gbi, h, nullptr, nullptr, DD, u, DP);

        // h = t @ lW + lb
        wconv<<<dim3((DP * DP + 255) / 256), blk, 0, stream>>>(lWi, DD, DD, 0, wbuf, DP, DP);
        gemm_mfma<5, 1, 0, 0, 0><<<dim3(2, rowBlocks), dim3(512), 0, stream>>>(
            u, DP, N, DP, wbuf, lbi, nullptr, nullptr, nullptr, DD, h, DP);
    }

    // ---- global mean pool + head ----
    zero_f<<<dim3((G * DD + 255) / 256), blk, 0, stream>>>(sums, G * DD);
    zero_f<<<dim3(1), blk, 0, stream>>>(cnts, G);
    pool_kernel<<<dim3((N + 127) / 128), dim3(320), 0, stream>>>(h, batch, sums, cnts, N, 128);
    head_kernel<<<dim3(1), dim3(256), 0, stream>>>(sums, cnts, dW, db, (float*)d_out);
}

// Round 3
// 940.346 us; speedup vs baseline: 5.1128x; 1.0277x over previous
//
#include <hip/hip_runtime.h>
#include <hip/hip_bf16.h>

#define DD 300
#define DP 320   // padded feature width

typedef unsigned short ushort_t;
typedef __attribute__((ext_vector_type(8))) short short8;
typedef __attribute__((ext_vector_type(4))) float f32x4;

__device__ __forceinline__ float b2f(ushort_t u) {
    unsigned x = ((unsigned)u) << 16;
    return __uint_as_float(x);
}
__device__ __forceinline__ ushort_t f2b(float f) {
    unsigned u = __float_as_uint(f);
    unsigned r = (u + 0x7FFFu + ((u >> 16) & 1u)) >> 16;
    return (ushort_t)r;
}

__device__ __forceinline__ void gload16(const void* g, void* l) {
    __builtin_amdgcn_global_load_lds((const __attribute__((address_space(1))) void*)g,
                                     (__attribute__((address_space(3))) void*)l, 16, 0, 0);
}

// ================= MFMA bf16 GEMM =================
// C[M][·] = A[M][K](bf16) @ Bt^T ; Bt is [Np][K] bf16 pre-transposed/padded.
// BM=128, BK=64, BN=32*BNT, 512 threads = 8 waves (4 row x 2 col)
template<int BNT, int BIAS, int RELU, int RESID, int RANK3>
__launch_bounds__(512)
__global__ void gemm_mfma(const ushort_t* __restrict__ A, int strideA, int M, int K,
                          const ushort_t* __restrict__ Bt,
                          const float* __restrict__ bias,
                          const ushort_t* __restrict__ resid,
                          const float* __restrict__ X3,
                          const float* __restrict__ W3,
                          int NCOL,
                          ushort_t* __restrict__ C, int strideC)
{
    constexpr int BM = 128, BK = 64, BN = 32 * BNT;
    constexpr int CA = BM * BK * 2 / 1024;
    constexpr int CB = BN * BK * 2 / 1024;
    __shared__ ushort_t As[BM * BK];
    __shared__ ushort_t Bs[BN * BK];

    const int tid = threadIdx.x;
    const int lane = tid & 63, wid = tid >> 6;
    const int rowTile = blockIdx.y * BM;
    const int colTile = blockIdx.x * BN;
    const int wm = wid >> 1, wn = wid & 1;

    const int lrow = lane >> 3;
    const int l8b = (lane & 7) * 16;

    f32x4 acc[2][BNT];
    #pragma unroll
    for (int f = 0; f < 2; ++f)
        #pragma unroll
        for (int q = 0; q < BNT; ++q) {
            f32x4 z = {0.f, 0.f, 0.f, 0.f};
            acc[f][q] = z;
        }

    for (int k0 = 0; k0 < K; k0 += BK) {
        for (int c = wid; c < CA; c += 8) {
            int row = c * 8 + lrow;
            int colb = l8b ^ ((row & 7) << 4);
            int gr = rowTile + row; if (gr > M - 1) gr = M - 1;
            gload16(A + (size_t)gr * strideA + k0 + (colb >> 1), As + c * 512);
        }
        for (int c = wid; c < CB; c += 8) {
            int row = c * 8 + lrow;
            int colb = l8b ^ ((row & 7) << 4);
            gload16(Bt + (size_t)(colTile + row) * K + k0 + (colb >> 1), Bs + c * 512);
        }
        __syncthreads();

        #pragma unroll
        for (int ks = 0; ks < 2; ++ks) {
            const int kidx = ks * 32 + (lane >> 4) * 8;
            short8 af[2], bf[BNT];
            #pragma unroll
            for (int f = 0; f < 2; ++f) {
                int row = wm * 32 + f * 16 + (lane & 15);
                int phys = (row * 128 + kidx * 2) ^ ((row & 7) << 4);
                af[f] = *(const short8*)((const char*)As + phys);
            }
            #pragma unroll
            for (int q = 0; q < BNT; ++q) {
                int row = wn * 16 * BNT + q * 16 + (lane & 15);
                int phys = (row * 128 + kidx * 2) ^ ((row & 7) << 4);
                bf[q] = *(const short8*)((const char*)Bs + phys);
            }
            #pragma unroll
            for (int f = 0; f < 2; ++f)
                #pragma unroll
                for (int q = 0; q < BNT; ++q)
                    acc[f][q] = __builtin_amdgcn_mfma_f32_16x16x32_bf16(af[f], bf[q], acc[f][q], 0, 0, 0);
        }
        __syncthreads();
    }

    #pragma unroll
    for (int f = 0; f < 2; ++f) {
        #pragma unroll
        for (int r = 0; r < 4; ++r) {
            int row = rowTile + wm * 32 + f * 16 + (lane >> 4) * 4 + r;
            if (row >= M) continue;
            #pragma unroll
            for (int q = 0; q < BNT; ++q) {
                int col = colTile + wn * 16 * BNT + q * 16 + (lane & 15);
                float v = acc[f][q][r];
                if (BIAS) v += bias[col];
                if (RANK3) {
                    if (col < NCOL) {
                        v += X3[row * 3 + 0] * W3[col]
                           + X3[row * 3 + 1] * W3[NCOL + col]
                           + X3[row * 3 + 2] * W3[2 * NCOL + col];
                    }
                }
                if (RESID) v += b2f(resid[(size_t)row * strideC + col]);
                if (RELU) v = fmaxf(v, 0.f);
                C[(size_t)row * strideC + col] = f2b(v);
            }
        }
    }
}

// ============ single prep kernel: all weight transposes + padded biases ============
// WU[i]: [320][320] rows<300 = fWh^T, rows 300-302 = hW^T (delta fused as extra cols)
// WG/WL: [320][320]  W2:[128][64]  W3e:[320][128]
__global__ void prep(const float* __restrict__ pW2, const float* __restrict__ pW3,
                     const float* __restrict__ pb3,
                     const float* __restrict__ hW, const float* __restrict__ hb,
                     const float* __restrict__ fW,
                     const float* __restrict__ gW, const float* __restrict__ gb,
                     const float* __restrict__ lW, const float* __restrict__ lb,
                     ushort_t* __restrict__ WU, ushort_t* __restrict__ WG,
                     ushort_t* __restrict__ WL, ushort_t* __restrict__ W2,
                     ushort_t* __restrict__ W3e,
                     float* __restrict__ bU, float* __restrict__ bG,
                     float* __restrict__ bL, float* __restrict__ b3)
{
    const int SZ = DP * DP;
    int idx = blockIdx.x * 256 + threadIdx.x;
    if (idx < 3 * SZ) {
        int i = idx / SZ, r = idx - i * SZ;
        int n = r / DP, k = r - n * DP;
        float v = 0.f;
        if (k < DD) {
            if (n < DD) v = fW[i * 90900 + (3 + k) * DD + n];
            else if (n < DD + 3) v = hW[i * 900 + k * 3 + (n - DD)];
        }
        WU[idx] = f2b(v);
        return;
    }
    idx -= 3 * SZ;
    if (idx < 3 * SZ) {
        int i = idx / SZ, r = idx - i * SZ;
        int n = r / DP, k = r - n * DP;
        float v = (n < DD && k < DD) ? gW[i * 90000 + k * DD + n] : 0.f;
        WG[idx] = f2b(v);
        return;
    }
    idx -= 3 * SZ;
    if (idx < 3 * SZ) {
        int i = idx / SZ, r = idx - i * SZ;
        int n = r / DP, k = r - n * DP;
        float v = (n < DD && k < DD) ? lW[i * 90000 + k * DD + n] : 0.f;
        WL[idx] = f2b(v);
        return;
    }
    idx -= 3 * SZ;
    if (idx < 128 * 64) {
        int n = idx >> 6, k = idx & 63;
        W2[idx] = f2b(pW2[k * 128 + n]);
        return;
    }
    idx -= 128 * 64;
    if (idx < DP * 128) {
        int n = idx >> 7, k = idx & 127;
        W3e[idx] = f2b((n < DD) ? pW3[k * DD + n] : 0.f);
        return;
    }
    idx -= DP * 128;
    if (idx < 3 * DP) {
        int i = idx / DP, n = idx - i * DP;
        bU[idx] = (n >= DD && n < DD + 3) ? hb[i * 3 + (n - DD)] : 0.f;
        return;
    }
    idx -= 3 * DP;
    if (idx < 3 * DP) {
        int i = idx / DP, n = idx - i * DP;
        bG[idx] = (n < DD) ? gb[i * DD + n] : 0.f;
        return;
    }
    idx -= 3 * DP;
    if (idx < 3 * DP) {
        int i = idx / DP, n = idx - i * DP;
        bL[idx] = (n < DD) ? lb[i * DD + n] : 0.f;
        return;
    }
    idx -= 3 * DP;
    if (idx < DP) {
        b3[idx] = (idx < DD) ? pb3[idx] : 0.f;
        return;
    }
}

// ============ embed layer 1: h1 = relu(x @ pW1 + pb1), K=3 ============
__global__ void embed1(const float* __restrict__ x, const float* __restrict__ W,
                       const float* __restrict__ b, ushort_t* __restrict__ h1, int M)
{
    int idx = blockIdx.x * 256 + threadIdx.x;
    if (idx >= M * 64) return;
    int n = idx >> 6, c = idx & 63;
    const float* xr = x + n * 3;
    float v = xr[0] * W[c] + xr[1] * W[64 + c] + xr[2] * W[128 + c] + b[c];
    h1[idx] = f2b(fmaxf(v, 0.f));
}

// ============ CSR build ============
__global__ void zero_i(int* __restrict__ p, int n)
{
    int i = blockIdx.x * 256 + threadIdx.x;
    if (i < n) p[i] = 0;
}
__global__ void zero_f(float* __restrict__ p, int n)
{
    int i = blockIdx.x * 256 + threadIdx.x;
    if (i < n) p[i] = 0.f;
}
__global__ void hist_kernel(const int* __restrict__ dst, int* __restrict__ cnt, int E)
{
    int e = blockIdx.x * 256 + threadIdx.x;
    if (e < E) atomicAdd(&cnt[dst[e]], 1);
}
__global__ void scan1(const int* __restrict__ cnt, int* __restrict__ bsum, int N)
{
    __shared__ int s[256];
    int t = threadIdx.x;
    int i = blockIdx.x * 256 + t;
    s[t] = (i < N) ? cnt[i] : 0;
    __syncthreads();
    for (int o = 128; o > 0; o >>= 1) { if (t < o) s[t] += s[t + o]; __syncthreads(); }
    if (t == 0) bsum[blockIdx.x] = s[0];
}
__global__ void scan2(int* __restrict__ bsum, int nb)
{
    __shared__ int s[256];
    int t = threadIdx.x;
    int v = (t < nb) ? bsum[t] : 0;
    s[t] = v; __syncthreads();
    for (int o = 1; o < 256; o <<= 1) {
        int x = (t >= o) ? s[t - o] : 0;
        __syncthreads();
        s[t] += x;
        __syncthreads();
    }
    if (t < nb) bsum[t] = s[t] - v;
}
__global__ void scan3(const int* __restrict__ cnt, const int* __restrict__ bsumx,
                      int* __restrict__ off, int* __restrict__ cursor, int N)
{
    __shared__ int s[256];
    int t = threadIdx.x;
    int i = blockIdx.x * 256 + t;
    int v = (i < N) ? cnt[i] : 0;
    s[t] = v; __syncthreads();
    for (int o = 1; o < 256; o <<= 1) {
        int x = (t >= o) ? s[t - o] : 0;
        __syncthreads();
        s[t] += x;
        __syncthreads();
    }
    int excl = s[t] - v + bsumx[blockIdx.x];
    if (i <= N) {
        off[i] = excl;
        if (i < N) cursor[i] = excl;
    }
}
__global__ void scatter_kernel(const int* __restrict__ src, const int* __restrict__ dst,
                               int* __restrict__ cursor, int* __restrict__ csr, int E)
{
    int e = blockIdx.x * 256 + threadIdx.x;
    if (e < E) {
        int p = atomicAdd(&cursor[dst[e]], 1);
        csr[p] = src[e];
    }
}

// ============ segment max over CSR, vectorized 16B loads, fused dst epilogue ============
// delta comes from u[n][300..302] (fused into the u-GEMM as extra output columns)
__global__ void segmax(const ushort_t* __restrict__ u, const int* __restrict__ off,
                       const int* __restrict__ csr,
                       const float* __restrict__ x, const float* __restrict__ fWp,
                       const float* __restrict__ fb, ushort_t* __restrict__ agg, int Nn)
{
    int n = blockIdx.x * 4 + (threadIdx.x >> 6);
    int lane = threadIdx.x & 63;
    if (n >= Nn) return;
    const int e0 = off[n], e1 = off[n + 1];
    const bool act = lane < 40;
    const size_t lb8 = (size_t)lane * 8;

    float m[8];
    #pragma unroll
    for (int j = 0; j < 8; ++j) m[j] = -INFINITY;

    int e = e0;
    for (; e + 3 < e1; e += 4) {
        int s0 = csr[e], s1 = csr[e + 1], s2 = csr[e + 2], s3 = csr[e + 3];
        if (act) {
            short8 v0 = *(const short8*)(u + (size_t)s0 * DP + lb8);
            short8 v1 = *(const short8*)(u + (size_t)s1 * DP + lb8);
            short8 v2 = *(const short8*)(u + (size_t)s2 * DP + lb8);
            short8 v3 = *(const short8*)(u + (size_t)s3 * DP + lb8);
            #pragma unroll
            for (int j = 0; j < 8; ++j) {
                m[j] = fmaxf(m[j], fmaxf(fmaxf(b2f((ushort_t)v0[j]), b2f((ushort_t)v1[j])),
                                         fmaxf(b2f((ushort_t)v2[j]), b2f((ushort_t)v3[j]))));
            }
        }
    }
    for (; e < e1; ++e) {
        int s0 = csr[e];
        if (act) {
            short8 v0 = *(const short8*)(u + (size_t)s0 * DP + lb8);
            #pragma unroll
            for (int j = 0; j < 8; ++j) m[j] = fmaxf(m[j], b2f((ushort_t)v0[j]));
        }
    }

    const ushort_t* un = u + (size_t)n * DP;
    float d0 = b2f(un[300]) - x[n * 3 + 0];
    float d1 = b2f(un[301]) - x[n * 3 + 1];
    float d2 = b2f(un[302]) - x[n * 3 + 2];

    if (act) {
        short8 o;
        #pragma unroll
        for (int j = 0; j < 8; ++j) {
            int col = lane * 8 + j;
            float v = 0.f;
            if (e1 > e0 && col < DD)
                v = m[j] + fb[col] + d0 * fWp[col] + d1 * fWp[DD + col] + d2 * fWp[2 * DD + col];
            o[j] = (short)f2b(v);
        }
        *(short8*)(agg + (size_t)n * DP + lb8) = o;
    }
}

// ============ global mean pool (bf16 h) ============
__global__ void pool_kernel(const ushort_t* __restrict__ h, const int* __restrict__ batch,
                            float* __restrict__ sums, float* __restrict__ cnts,
                            int Nn, int npb)
{
    int c = threadIdx.x;
    int n0 = blockIdx.x * npb;
    int n1 = min(n0 + npb, Nn);
    if (n0 >= n1) return;
    if (c < DD) {
        float run = 0.f;
        int g = batch[n0];
        for (int n = n0; n < n1; ++n) {
            int gn = batch[n];
            if (gn != g) { atomicAdd(&sums[g * DD + c], run); run = 0.f; g = gn; }
            run += b2f(h[(size_t)n * DP + c]);
        }
        atomicAdd(&sums[g * DD + c], run);
    } else if (c == DD) {
        float run = 0.f;
        int g = batch[n0];
        for (int n = n0; n < n1; ++n) {
            int gn = batch[n];
            if (gn != g) { atomicAdd(&cnts[g], run); run = 0.f; g = gn; }
            run += 1.f;
        }
        atomicAdd(&cnts[g], run);
    }
}

// ============ head: mean -> logits -> log_softmax ============
__global__ void head_kernel(const float* __restrict__ sums, const float* __restrict__ cnts,
                            const float* __restrict__ dW, const float* __restrict__ db,
                            float* __restrict__ out)
{
    __shared__ float mean[32][DD];
    __shared__ float logits[32][40];
    int tid = threadIdx.x;
    for (int i = tid; i < 32 * DD; i += 256) {
        int g = i / DD;
        mean[g][i - g * DD] = sums[i] / fmaxf(cnts[g], 1.f);
    }
    __syncthreads();
    for (int o = tid; o < 32 * 40; o += 256) {
        int g = o / 40, cls = o - g * 40;
        float acc = db[cls];
        for (int k = 0; k < DD; ++k) acc += mean[g][k] * dW[k * 40 + cls];
        logits[g][cls] = acc;
    }
    __syncthreads();
    if (tid < 32) {
        float mx = -INFINITY;
        #pragma unroll
        for (int j = 0; j < 40; ++j) mx = fmaxf(mx, logits[tid][j]);
        float se = 0.f;
        for (int j = 0; j < 40; ++j) se += expf(logits[tid][j] - mx);
        float lse = mx + logf(se);
        for (int j = 0; j < 40; ++j) out[tid * 40 + j] = logits[tid][j] - lse;
    }
}

extern "C" void kernel_launch(void* const* d_in, const int* in_sizes, int n_in,
                              void* d_out, int out_size, void* d_ws, size_t ws_size,
                              hipStream_t stream)
{
    const float* x     = (const float*)d_in[0];
    const int*   ei    = (const int*)d_in[1];
    const int*   batch = (const int*)d_in[2];
    const float* pW1   = (const float*)d_in[3];
    const float* pb1   = (const float*)d_in[4];
    const float* pW2   = (const float*)d_in[5];
    const float* pb2   = (const float*)d_in[6];
    const float* pW3   = (const float*)d_in[7];
    const float* pb3   = (const float*)d_in[8];
    const float* hW    = (const float*)d_in[9];
    const float* hb    = (const float*)d_in[10];
    const float* fW    = (const float*)d_in[11];
    const float* fb    = (const float*)d_in[12];
    const float* gW    = (const float*)d_in[13];
    const float* gb    = (const float*)d_in[14];
    const float* lW    = (const float*)d_in[15];
    const float* lb    = (const float*)d_in[16];
    const float* dW    = (const float*)d_in[17];
    const float* db    = (const float*)d_in[18];

    const int N = in_sizes[0] / 3;
    const int E = in_sizes[1] / 2;
    const int G = 32;
    (void)ws_size; (void)n_in; (void)out_size;

    char* wsb = (char*)d_ws;
    size_t offb = 0;
    auto alloc = [&](size_t bytes) {
        void* p = wsb + offb;
        offb += (bytes + 255) & ~(size_t)255;
        return p;
    };
    ushort_t* h    = (ushort_t*)alloc((size_t)N * DP * 2);
    ushort_t* u    = (ushort_t*)alloc((size_t)N * DP * 2);
    ushort_t* agg  = (ushort_t*)alloc((size_t)N * DP * 2);
    ushort_t* h1   = (ushort_t*)alloc((size_t)N * 64 * 2);
    ushort_t* h2   = (ushort_t*)alloc((size_t)N * 128 * 2);
    const int SZ = DP * DP;
    ushort_t* WU   = (ushort_t*)alloc((size_t)3 * SZ * 2);
    ushort_t* WG   = (ushort_t*)alloc((size_t)3 * SZ * 2);
    ushort_t* WL   = (ushort_t*)alloc((size_t)3 * SZ * 2);
    ushort_t* W2   = (ushort_t*)alloc((size_t)128 * 64 * 2);
    ushort_t* W3e  = (ushort_t*)alloc((size_t)DP * 128 * 2);
    float*    bU   = (float*)alloc((size_t)3 * DP * 4);
    float*    bG   = (float*)alloc((size_t)3 * DP * 4);
    float*    bL   = (float*)alloc((size_t)3 * DP * 4);
    float*    b3   = (float*)alloc((size_t)DP * 4);
    int*      cnt    = (int*)alloc((size_t)(N + 1) * 4);
    int*      offp   = (int*)alloc((size_t)(N + 1) * 4);
    int*      cursor = (int*)alloc((size_t)N * 4);
    int*      bsum   = (int*)alloc((size_t)256 * 4);
    int*      csr    = (int*)alloc((size_t)E * 4);
    float*    sums   = (float*)alloc((size_t)G * DD * 4);
    float*    cnts   = (float*)alloc((size_t)G * 4);

    const int* srcp = ei;
    const int* dstp = ei + E;
    const int nb = (N + 255) / 256;
    const dim3 blk(256);

    // ---- prep (all weight conversions, one launch) ----
    const int prepTotal = 3 * SZ * 3 + 128 * 64 + DP * 128 + 3 * DP * 3 + DP;
    prep<<<dim3((prepTotal + 255) / 256), blk, 0, stream>>>(
        pW2, pW3, pb3, hW, hb, fW, gW, gb, lW, lb,
        WU, WG, WL, W2, W3e, bU, bG, bL, b3);

    // ---- CSR build ----
    zero_i<<<dim3((N + 1 + 255) / 256), blk, 0, stream>>>(cnt, N + 1);
    hist_kernel<<<dim3((E + 255) / 256), blk, 0, stream>>>(dstp, cnt, E);
    scan1<<<dim3(nb), blk, 0, stream>>>(cnt, bsum, N);
    scan2<<<dim3(1), blk, 0, stream>>>(bsum, nb);
    scan3<<<dim3(nb), blk, 0, stream>>>(cnt, bsum, offp, cursor, N);
    scatter_kernel<<<dim3((E + 255) / 256), blk, 0, stream>>>(srcp, dstp, cursor, csr, E);

    // ---- embed MLP ----
    embed1<<<dim3((N * 64 + 255) / 256), blk, 0, stream>>>(x, pW1, pb1, h1, N);

    const int rowBlocks = (N + 127) / 128;
    gemm_mfma<4, 1, 1, 0, 0><<<dim3(1, rowBlocks), dim3(512), 0, stream>>>(
        h1, 64, N, 64, W2, pb2, nullptr, nullptr, nullptr, 128, h2, 128);
    gemm_mfma<5, 1, 0, 0, 0><<<dim3(2, rowBlocks), dim3(512), 0, stream>>>(
        h2, 128, N, 128, W3e, b3, nullptr, nullptr, nullptr, DD, h, DP);

    // ---- 3 PointGNNConv layers ----
    for (int i = 0; i < 3; ++i) {
        const float* fWi = fW + (size_t)i * (DD + 3) * DD;
        const float* fbi = fb + (size_t)i * DD;

        // u = h @ fWh + x @ fWp ; cols 300-302 = delta = h @ hW + hb (fused)
        gemm_mfma<5, 1, 0, 0, 1><<<dim3(2, rowBlocks), dim3(512), 0, stream>>>(
            h, DP, N, DP, WU + (size_t)i * SZ, bU + (size_t)i * DP,
            nullptr, x, fWi, DD, u, DP);

        // agg = segment_max(u[src], dst) + fb + (delta-pos)@fWp
        segmax<<<dim3((N + 3) / 4), blk, 0, stream>>>(u, offp, csr, x, fWi, fbi, agg, N);

        // t = relu(agg @ gW + gb + h) -> u buffer
        gemm_mfma<5, 1, 1, 1, 0><<<dim3(2, rowBlocks), dim3(512), 0, stream>>>(
            agg, DP, N, DP, WG + (size_t)i * SZ, bG + (size_t)i * DP,
            h, nullptr, nullptr, DD, u, DP);

        // h = t @ lW + lb
        gemm_mfma<5, 1, 0, 0, 0><<<dim3(2, rowBlocks), dim3(512), 0, stream>>>(
            u, DP, N, DP, WL + (size_t)i * SZ, bL + (size_t)i * DP,
            nullptr, nullptr, nullptr, DD, h, DP);
    }

    // ---- global mean pool + head ----
    zero_f<<<dim3((G * DD + 255) / 256), blk, 0, stream>>>(sums, G * DD);
    zero_f<<<dim3(1), blk, 0, stream>>>(cnts, G);
    pool_kernel<<<dim3((N + 127) / 128), dim3(320), 0, stream>>>(h, batch, sums, cnts, N, 128);
    head_kernel<<<dim3(1), dim3(256), 0, stream>>>(sums, cnts, dW, db, (float*)d_out);
}

// Round 4
// 727.813 us; speedup vs baseline: 6.6059x; 1.2920x over previous
//
#include <hip/hip_runtime.h>
#include <hip/hip_bf16.h>

#define DD 300
#define DP 320   // padded feature width

typedef unsigned short ushort_t;
typedef __attribute__((ext_vector_type(8))) short short8;
typedef __attribute__((ext_vector_type(4))) float f32x4;

__device__ __forceinline__ float b2f(ushort_t u) {
    unsigned x = ((unsigned)u) << 16;
    return __uint_as_float(x);
}
__device__ __forceinline__ ushort_t f2b(float f) {
    unsigned u = __float_as_uint(f);
    unsigned r = (u + 0x7FFFu + ((u >> 16) & 1u)) >> 16;
    return (ushort_t)r;
}

__device__ __forceinline__ void gload16(const void* g, void* l) {
    __builtin_amdgcn_global_load_lds((const __attribute__((address_space(1))) void*)g,
                                     (__attribute__((address_space(3))) void*)l, 16, 0, 0);
}

// ================= MFMA bf16 GEMM =================
// C[M][·] = A[M][K](bf16) @ Bt^T ; Bt is [Np][K] bf16 pre-transposed/padded.
// BM=128, BK=64, BN=32*BNT, 512 threads = 8 waves (4 row x 2 col)
template<int BNT, int BIAS, int RELU, int RESID, int RANK3>
__launch_bounds__(512)
__global__ void gemm_mfma(const ushort_t* __restrict__ A, int strideA, int M, int K,
                          const ushort_t* __restrict__ Bt,
                          const float* __restrict__ bias,
                          const ushort_t* __restrict__ resid,
                          const float* __restrict__ X3,
                          const float* __restrict__ W3,
                          int NCOL,
                          ushort_t* __restrict__ C, int strideC)
{
    constexpr int BM = 128, BK = 64, BN = 32 * BNT;
    constexpr int CA = BM * BK * 2 / 1024;
    constexpr int CB = BN * BK * 2 / 1024;
    __shared__ ushort_t As[BM * BK];
    __shared__ ushort_t Bs[BN * BK];

    const int tid = threadIdx.x;
    const int lane = tid & 63, wid = tid >> 6;
    const int rowTile = blockIdx.y * BM;
    const int colTile = blockIdx.x * BN;
    const int wm = wid >> 1, wn = wid & 1;

    const int lrow = lane >> 3;
    const int l8b = (lane & 7) * 16;

    f32x4 acc[2][BNT];
    #pragma unroll
    for (int f = 0; f < 2; ++f)
        #pragma unroll
        for (int q = 0; q < BNT; ++q) {
            f32x4 z = {0.f, 0.f, 0.f, 0.f};
            acc[f][q] = z;
        }

    for (int k0 = 0; k0 < K; k0 += BK) {
        for (int c = wid; c < CA; c += 8) {
            int row = c * 8 + lrow;
            int colb = l8b ^ ((row & 7) << 4);
            int gr = rowTile + row; if (gr > M - 1) gr = M - 1;
            gload16(A + (size_t)gr * strideA + k0 + (colb >> 1), As + c * 512);
        }
        for (int c = wid; c < CB; c += 8) {
            int row = c * 8 + lrow;
            int colb = l8b ^ ((row & 7) << 4);
            gload16(Bt + (size_t)(colTile + row) * K + k0 + (colb >> 1), Bs + c * 512);
        }
        __syncthreads();

        #pragma unroll
        for (int ks = 0; ks < 2; ++ks) {
            const int kidx = ks * 32 + (lane >> 4) * 8;
            short8 af[2], bf[BNT];
            #pragma unroll
            for (int f = 0; f < 2; ++f) {
                int row = wm * 32 + f * 16 + (lane & 15);
                int phys = (row * 128 + kidx * 2) ^ ((row & 7) << 4);
                af[f] = *(const short8*)((const char*)As + phys);
            }
            #pragma unroll
            for (int q = 0; q < BNT; ++q) {
                int row = wn * 16 * BNT + q * 16 + (lane & 15);
                int phys = (row * 128 + kidx * 2) ^ ((row & 7) << 4);
                bf[q] = *(const short8*)((const char*)Bs + phys);
            }
            #pragma unroll
            for (int f = 0; f < 2; ++f)
                #pragma unroll
                for (int q = 0; q < BNT; ++q)
                    acc[f][q] = __builtin_amdgcn_mfma_f32_16x16x32_bf16(af[f], bf[q], acc[f][q], 0, 0, 0);
        }
        __syncthreads();
    }

    #pragma unroll
    for (int f = 0; f < 2; ++f) {
        #pragma unroll
        for (int r = 0; r < 4; ++r) {
            int row = rowTile + wm * 32 + f * 16 + (lane >> 4) * 4 + r;
            if (row >= M) continue;
            #pragma unroll
            for (int q = 0; q < BNT; ++q) {
                int col = colTile + wn * 16 * BNT + q * 16 + (lane & 15);
                float v = acc[f][q][r];
                if (BIAS) v += bias[col];
                if (RANK3) {
                    if (col < NCOL) {
                        v += X3[row * 3 + 0] * W3[col]
                           + X3[row * 3 + 1] * W3[NCOL + col]
                           + X3[row * 3 + 2] * W3[2 * NCOL + col];
                    }
                }
                if (RESID) v += b2f(resid[(size_t)row * strideC + col]);
                if (RELU) v = fmaxf(v, 0.f);
                C[(size_t)row * strideC + col] = f2b(v);
            }
        }
    }
}

// ============ single prep kernel: all weight transposes + padded biases ============
__global__ void prep(const float* __restrict__ pW2, const float* __restrict__ pW3,
                     const float* __restrict__ pb3,
                     const float* __restrict__ hW, const float* __restrict__ hb,
                     const float* __restrict__ fW,
                     const float* __restrict__ gW, const float* __restrict__ gb,
                     const float* __restrict__ lW, const float* __restrict__ lb,
                     ushort_t* __restrict__ WU, ushort_t* __restrict__ WG,
                     ushort_t* __restrict__ WL, ushort_t* __restrict__ W2,
                     ushort_t* __restrict__ W3e,
                     float* __restrict__ bU, float* __restrict__ bG,
                     float* __restrict__ bL, float* __restrict__ b3)
{
    const int SZ = DP * DP;
    int idx = blockIdx.x * 256 + threadIdx.x;
    if (idx < 3 * SZ) {
        int i = idx / SZ, r = idx - i * SZ;
        int n = r / DP, k = r - n * DP;
        float v = 0.f;
        if (k < DD) {
            if (n < DD) v = fW[i * 90900 + (3 + k) * DD + n];
            else if (n < DD + 3) v = hW[i * 900 + k * 3 + (n - DD)];
        }
        WU[idx] = f2b(v);
        return;
    }
    idx -= 3 * SZ;
    if (idx < 3 * SZ) {
        int i = idx / SZ, r = idx - i * SZ;
        int n = r / DP, k = r - n * DP;
        float v = (n < DD && k < DD) ? gW[i * 90000 + k * DD + n] : 0.f;
        WG[idx] = f2b(v);
        return;
    }
    idx -= 3 * SZ;
    if (idx < 3 * SZ) {
        int i = idx / SZ, r = idx - i * SZ;
        int n = r / DP, k = r - n * DP;
        float v = (n < DD && k < DD) ? lW[i * 90000 + k * DD + n] : 0.f;
        WL[idx] = f2b(v);
        return;
    }
    idx -= 3 * SZ;
    if (idx < 128 * 64) {
        int n = idx >> 6, k = idx & 63;
        W2[idx] = f2b(pW2[k * 128 + n]);
        return;
    }
    idx -= 128 * 64;
    if (idx < DP * 128) {
        int n = idx >> 7, k = idx & 127;
        W3e[idx] = f2b((n < DD) ? pW3[k * DD + n] : 0.f);
        return;
    }
    idx -= DP * 128;
    if (idx < 3 * DP) {
        int i = idx / DP, n = idx - i * DP;
        bU[idx] = (n >= DD && n < DD + 3) ? hb[i * 3 + (n - DD)] : 0.f;
        return;
    }
    idx -= 3 * DP;
    if (idx < 3 * DP) {
        int i = idx / DP, n = idx - i * DP;
        bG[idx] = (n < DD) ? gb[i * DD + n] : 0.f;
        return;
    }
    idx -= 3 * DP;
    if (idx < 3 * DP) {
        int i = idx / DP, n = idx - i * DP;
        bL[idx] = (n < DD) ? lb[i * DD + n] : 0.f;
        return;
    }
    idx -= 3 * DP;
    if (idx < DP) {
        b3[idx] = (idx < DD) ? pb3[idx] : 0.f;
        return;
    }
}

// ============ embed layer 1: h1 = relu(x @ pW1 + pb1), K=3 ============
__global__ void embed1(const float* __restrict__ x, const float* __restrict__ W,
                       const float* __restrict__ b, ushort_t* __restrict__ h1, int M)
{
    int idx = blockIdx.x * 256 + threadIdx.x;
    if (idx >= M * 64) return;
    int n = idx >> 6, c = idx & 63;
    const float* xr = x + n * 3;
    float v = xr[0] * W[c] + xr[1] * W[64 + c] + xr[2] * W[128 + c] + b[c];
    h1[idx] = f2b(fmaxf(v, 0.f));
}

// ============ CSR build ============
__global__ void zero_i(int* __restrict__ p, int n)
{
    int i = blockIdx.x * 256 + threadIdx.x;
    if (i < n) p[i] = 0;
}
__global__ void zero_f(float* __restrict__ p, int n)
{
    int i = blockIdx.x * 256 + threadIdx.x;
    if (i < n) p[i] = 0.f;
}
__global__ void hist_kernel(const int* __restrict__ dst, int* __restrict__ cnt, int E)
{
    int e = blockIdx.x * 256 + threadIdx.x;
    if (e < E) atomicAdd(&cnt[dst[e]], 1);
}
__global__ void scan1(const int* __restrict__ cnt, int* __restrict__ bsum, int N)
{
    __shared__ int s[256];
    int t = threadIdx.x;
    int i = blockIdx.x * 256 + t;
    s[t] = (i < N) ? cnt[i] : 0;
    __syncthreads();
    for (int o = 128; o > 0; o >>= 1) { if (t < o) s[t] += s[t + o]; __syncthreads(); }
    if (t == 0) bsum[blockIdx.x] = s[0];
}
__global__ void scan2(int* __restrict__ bsum, int nb)
{
    __shared__ int s[256];
    int t = threadIdx.x;
    int v = (t < nb) ? bsum[t] : 0;
    s[t] = v; __syncthreads();
    for (int o = 1; o < 256; o <<= 1) {
        int x = (t >= o) ? s[t - o] : 0;
        __syncthreads();
        s[t] += x;
        __syncthreads();
    }
    if (t < nb) bsum[t] = s[t] - v;
}
__global__ void scan3(const int* __restrict__ cnt, const int* __restrict__ bsumx,
                      int* __restrict__ off, int* __restrict__ cursor, int N)
{
    __shared__ int s[256];
    int t = threadIdx.x;
    int i = blockIdx.x * 256 + t;
    int v = (i < N) ? cnt[i] : 0;
    s[t] = v; __syncthreads();
    for (int o = 1; o < 256; o <<= 1) {
        int x = (t >= o) ? s[t - o] : 0;
        __syncthreads();
        s[t] += x;
        __syncthreads();
    }
    int excl = s[t] - v + bsumx[blockIdx.x];
    if (i <= N) {
        off[i] = excl;
        if (i < N) cursor[i] = excl;
    }
}
__global__ void scatter_kernel(const int* __restrict__ src, const int* __restrict__ dst,
                               int* __restrict__ cursor, int* __restrict__ csr, int E)
{
    int e = blockIdx.x * 256 + threadIdx.x;
    if (e < E) {
        int p = atomicAdd(&cursor[dst[e]], 1);
        csr[p] = src[e];
    }
}

// ============ segment max over CSR ============
// All 64 lanes active, scalar coalesced 2B loads (5 per lane per edge = 5x128B
// lines per instruction-group), 4-edge branch-free unroll -> 20 independent
// lines in flight per wave. delta comes from u[n][300..302] (fused in GEMM).
__global__ void segmax(const ushort_t* __restrict__ u, const int* __restrict__ off,
                       const int* __restrict__ csr,
                       const float* __restrict__ x, const float* __restrict__ fWp,
                       const float* __restrict__ fb, ushort_t* __restrict__ agg, int Nn)
{
    int n = blockIdx.x * 4 + (threadIdx.x >> 6);
    int lane = threadIdx.x & 63;
    if (n >= Nn) return;
    const int e0 = off[n], e1 = off[n + 1];

    // hoist dst-side terms so their latency overlaps the edge loop
    const ushort_t* un = u + (size_t)n * DP;
    float d0 = b2f(un[300]) - x[n * 3 + 0];
    float d1 = b2f(un[301]) - x[n * 3 + 1];
    float d2 = b2f(un[302]) - x[n * 3 + 2];

    float m[5];
    #pragma unroll
    for (int j = 0; j < 5; ++j) m[j] = -INFINITY;

    int e = e0;
    for (; e + 3 < e1; e += 4) {
        const ushort_t* r0 = u + (size_t)csr[e]     * DP + lane;
        const ushort_t* r1 = u + (size_t)csr[e + 1] * DP + lane;
        const ushort_t* r2 = u + (size_t)csr[e + 2] * DP + lane;
        const ushort_t* r3 = u + (size_t)csr[e + 3] * DP + lane;
        #pragma unroll
        for (int j = 0; j < 5; ++j) {
            float a = fmaxf(b2f(r0[64 * j]), b2f(r1[64 * j]));
            float b = fmaxf(b2f(r2[64 * j]), b2f(r3[64 * j]));
            m[j] = fmaxf(m[j], fmaxf(a, b));
        }
    }
    for (; e < e1; ++e) {
        const ushort_t* r0 = u + (size_t)csr[e] * DP + lane;
        #pragma unroll
        for (int j = 0; j < 5; ++j) m[j] = fmaxf(m[j], b2f(r0[64 * j]));
    }

    #pragma unroll
    for (int j = 0; j < 5; ++j) {
        int col = lane + 64 * j;
        float o = 0.f;
        if (e1 > e0 && col < DD)
            o = m[j] + fb[col] + d0 * fWp[col] + d1 * fWp[DD + col] + d2 * fWp[2 * DD + col];
        agg[(size_t)n * DP + col] = f2b(o);
    }
}

// ============ global mean pool (bf16 h) ============
__global__ void pool_kernel(const ushort_t* __restrict__ h, const int* __restrict__ batch,
                            float* __restrict__ sums, float* __restrict__ cnts,
                            int Nn, int npb)
{
    int c = threadIdx.x;
    int n0 = blockIdx.x * npb;
    int n1 = min(n0 + npb, Nn);
    if (n0 >= n1) return;
    if (c < DD) {
        float run = 0.f;
        int g = batch[n0];
        for (int n = n0; n < n1; ++n) {
            int gn = batch[n];
            if (gn != g) { atomicAdd(&sums[g * DD + c], run); run = 0.f; g = gn; }
            run += b2f(h[(size_t)n * DP + c]);
        }
        atomicAdd(&sums[g * DD + c], run);
    } else if (c == DD) {
        float run = 0.f;
        int g = batch[n0];
        for (int n = n0; n < n1; ++n) {
            int gn = batch[n];
            if (gn != g) { atomicAdd(&cnts[g], run); run = 0.f; g = gn; }
            run += 1.f;
        }
        atomicAdd(&cnts[g], run);
    }
}

// ============ head: mean -> logits -> log_softmax ============
__global__ void head_kernel(const float* __restrict__ sums, const float* __restrict__ cnts,
                            const float* __restrict__ dW, const float* __restrict__ db,
                            float* __restrict__ out)
{
    __shared__ float mean[32][DD];
    __shared__ float logits[32][40];
    int tid = threadIdx.x;
    for (int i = tid; i < 32 * DD; i += 256) {
        int g = i / DD;
        mean[g][i - g * DD] = sums[i] / fmaxf(cnts[g], 1.f);
    }
    __syncthreads();
    for (int o = tid; o < 32 * 40; o += 256) {
        int g = o / 40, cls = o - g * 40;
        float acc = db[cls];
        for (int k = 0; k < DD; ++k) acc += mean[g][k] * dW[k * 40 + cls];
        logits[g][cls] = acc;
    }
    __syncthreads();
    if (tid < 32) {
        float mx = -INFINITY;
        #pragma unroll
        for (int j = 0; j < 40; ++j) mx = fmaxf(mx, logits[tid][j]);
        float se = 0.f;
        for (int j = 0; j < 40; ++j) se += expf(logits[tid][j] - mx);
        float lse = mx + logf(se);
        for (int j = 0; j < 40; ++j) out[tid * 40 + j] = logits[tid][j] - lse;
    }
}

extern "C" void kernel_launch(void* const* d_in, const int* in_sizes, int n_in,
                              void* d_out, int out_size, void* d_ws, size_t ws_size,
                              hipStream_t stream)
{
    const float* x     = (const float*)d_in[0];
    const int*   ei    = (const int*)d_in[1];
    const int*   batch = (const int*)d_in[2];
    const float* pW1   = (const float*)d_in[3];
    const float* pb1   = (const float*)d_in[4];
    const float* pW2   = (const float*)d_in[5];
    const float* pb2   = (const float*)d_in[6];
    const float* pW3   = (const float*)d_in[7];
    const float* pb3   = (const float*)d_in[8];
    const float* hW    = (const float*)d_in[9];
    const float* hb    = (const float*)d_in[10];
    const float* fW    = (const float*)d_in[11];
    const float* fb    = (const float*)d_in[12];
    const float* gW    = (const float*)d_in[13];
    const float* gb    = (const float*)d_in[14];
    const float* lW    = (const float*)d_in[15];
    const float* lb    = (const float*)d_in[16];
    const float* dW    = (const float*)d_in[17];
    const float* db    = (const float*)d_in[18];

    const int N = in_sizes[0] / 3;
    const int E = in_sizes[1] / 2;
    const int G = 32;
    (void)ws_size; (void)n_in; (void)out_size;

    char* wsb = (char*)d_ws;
    size_t offb = 0;
    auto alloc = [&](size_t bytes) {
        void* p = wsb + offb;
        offb += (bytes + 255) & ~(size_t)255;
        return p;
    };
    ushort_t* h    = (ushort_t*)alloc((size_t)N * DP * 2);
    ushort_t* u    = (ushort_t*)alloc((size_t)N * DP * 2);
    ushort_t* agg  = (ushort_t*)alloc((size_t)N * DP * 2);
    ushort_t* h1   = (ushort_t*)alloc((size_t)N * 64 * 2);
    ushort_t* h2   = (ushort_t*)alloc((size_t)N * 128 * 2);
    const int SZ = DP * DP;
    ushort_t* WU   = (ushort_t*)alloc((size_t)3 * SZ * 2);
    ushort_t* WG   = (ushort_t*)alloc((size_t)3 * SZ * 2);
    ushort_t* WL   = (ushort_t*)alloc((size_t)3 * SZ * 2);
    ushort_t* W2   = (ushort_t*)alloc((size_t)128 * 64 * 2);
    ushort_t* W3e  = (ushort_t*)alloc((size_t)DP * 128 * 2);
    float*    bU   = (float*)alloc((size_t)3 * DP * 4);
    float*    bG   = (float*)alloc((size_t)3 * DP * 4);
    float*    bL   = (float*)alloc((size_t)3 * DP * 4);
    float*    b3   = (float*)alloc((size_t)DP * 4);
    int*      cnt    = (int*)alloc((size_t)(N + 1) * 4);
    int*      offp   = (int*)alloc((size_t)(N + 1) * 4);
    int*      cursor = (int*)alloc((size_t)N * 4);
    int*      bsum   = (int*)alloc((size_t)256 * 4);
    int*      csr    = (int*)alloc((size_t)E * 4);
    float*    sums   = (float*)alloc((size_t)G * DD * 4);
    float*    cnts   = (float*)alloc((size_t)G * 4);

    const int* srcp = ei;
    const int* dstp = ei + E;
    const int nb = (N + 255) / 256;
    const dim3 blk(256);

    // ---- prep (all weight conversions, one launch) ----
    const int prepTotal = 3 * SZ * 3 + 128 * 64 + DP * 128 + 3 * DP * 3 + DP;
    prep<<<dim3((prepTotal + 255) / 256), blk, 0, stream>>>(
        pW2, pW3, pb3, hW, hb, fW, gW, gb, lW, lb,
        WU, WG, WL, W2, W3e, bU, bG, bL, b3);

    // ---- CSR build ----
    zero_i<<<dim3((N + 1 + 255) / 256), blk, 0, stream>>>(cnt, N + 1);
    hist_kernel<<<dim3((E + 255) / 256), blk, 0, stream>>>(dstp, cnt, E);
    scan1<<<dim3(nb), blk, 0, stream>>>(cnt, bsum, N);
    scan2<<<dim3(1), blk, 0, stream>>>(bsum, nb);
    scan3<<<dim3(nb), blk, 0, stream>>>(cnt, bsum, offp, cursor, N);
    scatter_kernel<<<dim3((E + 255) / 256), blk, 0, stream>>>(srcp, dstp, cursor, csr, E);

    // ---- embed MLP ----
    embed1<<<dim3((N * 64 + 255) / 256), blk, 0, stream>>>(x, pW1, pb1, h1, N);

    const int rowBlocks = (N + 127) / 128;
    gemm_mfma<4, 1, 1, 0, 0><<<dim3(1, rowBlocks), dim3(512), 0, stream>>>(
        h1, 64, N, 64, W2, pb2, nullptr, nullptr, nullptr, 128, h2, 128);
    gemm_mfma<5, 1, 0, 0, 0><<<dim3(2, rowBlocks), dim3(512), 0, stream>>>(
        h2, 128, N, 128, W3e, b3, nullptr, nullptr, nullptr, DD, h, DP);

    // ---- 3 PointGNNConv layers ----
    for (int i = 0; i < 3; ++i) {
        const float* fWi = fW + (size_t)i * (DD + 3) * DD;
        const float* fbi = fb + (size_t)i * DD;

        // u = h @ fWh + x @ fWp ; cols 300-302 = delta = h @ hW + hb (fused)
        gemm_mfma<5, 1, 0, 0, 1><<<dim3(2, rowBlocks), dim3(512), 0, stream>>>(
            h, DP, N, DP, WU + (size_t)i * SZ, bU + (size_t)i * DP,
            nullptr, x, fWi, DD, u, DP);

        // agg = segment_max(u[src], dst) + fb + (delta-pos)@fWp
        segmax<<<dim3((N + 3) / 4), blk, 0, stream>>>(u, offp, csr, x, fWi, fbi, agg, N);

        // t = relu(agg @ gW + gb + h) -> u buffer
        gemm_mfma<5, 1, 1, 1, 0><<<dim3(2, rowBlocks), dim3(512), 0, stream>>>(
            agg, DP, N, DP, WG + (size_t)i * SZ, bG + (size_t)i * DP,
            h, nullptr, nullptr, DD, u, DP);

        // h = t @ lW + lb
        gemm_mfma<5, 1, 0, 0, 0><<<dim3(2, rowBlocks), dim3(512), 0, stream>>>(
            u, DP, N, DP, WL + (size_t)i * SZ, bL + (size_t)i * DP,
            nullptr, nullptr, nullptr, DD, h, DP);
    }

    // ---- global mean pool + head ----
    zero_f<<<dim3((G * DD + 255) / 256), blk, 0, stream>>>(sums, G * DD);
    zero_f<<<dim3(1), blk, 0, stream>>>(cnts, G);
    pool_kernel<<<dim3((N + 127) / 128), dim3(320), 0, stream>>>(h, batch, sums, cnts, N, 128);
    head_kernel<<<dim3(1), dim3(256), 0, stream>>>(sums, cnts, dW, db, (float*)d_out);
}